// Round 9
// baseline (76.936 us; speedup 1.0000x reference)
//
#include <hip/hip_runtime.h>
#include <math.h>

// VectorExpansionCalculator: per-edge radial basis (8 sines w/ cosine cutoff)
// outer-product with real spherical harmonics l=0..3 (n_max = 8,7,6,5).
// Output f32 blocks concat flat: [E,1,8] | [E,3,7] | [E,5,6] | [E,7,5].
// R1: scattered stores 137us. R2: LDS staging 79us. R3/R4: native sin, nt
// stores, staged s0 -> 74.9us. R5 XCD swizzle: refuted. R6 persistent grid:
// refuted. R7 per-section kernels: 74.7 (null). R8 fused section-partition:
// 73.2us (best).
// R9 (this): A/B — PLAIN stores instead of nontemporal, on the R8 base.
// nt has been bundled in since R3 without isolation; hypothesis: nt defeats
// L2 write-aggregation (evict-early -> fragmented HBM bursts), a flat ~20%
// write-path penalty that explains the structure-independent 5.3 TB/s wall.

#define RCUT 5.0f
#define EPSF 1e-12f

typedef float fx4 __attribute__((ext_vector_type(4)));

__device__ __forceinline__ void radial(float rr, float ir, float rb[8]) {
  float theta = (3.14159265358979323846f / RCUT) * rr;
  float s = __sinf(theta);
  float c = __cosf(theta);
  float fcut = (rr < RCUT) ? 0.5f * (c + 1.0f) : 0.0f;
  float g = fcut * ir;
  float twoc = 2.0f * c;
  float sp = 0.0f, sn = s;
  rb[0] = sn * g;
#pragma unroll
  for (int n = 1; n < 8; ++n) {
    float s2 = twoc * sn - sp;
    sp = sn;
    sn = s2;
    rb[n] = sn * g;
  }
}

// Sections 1..3: one 256-edge task per block (4 waves x 64 edges); stage
// 64 x S floats in wave-private LDS, flush as contiguous plain 16B stores.
template <int L>
__device__ __forceinline__ void do_section(const float* __restrict__ v,
                                           float* __restrict__ secbase, int E,
                                           int task, fx4* __restrict__ l4,
                                           int lane, int wave) {
  constexpr int M = 2 * L + 1;  // SH count
  constexpr int NM = 8 - L;     // n_max for this l
  constexpr int S = M * NM;     // floats per edge
  const long long e0 = ((long long)task * 4 + wave) * 64;
  if (e0 >= E) return;
  const bool fullwave = (e0 + 64 <= (long long)E);
  const int e = (int)e0 + lane;
  const bool valid = e < E;

  float x = 0.0f, y = 0.0f, z = 0.0f;
  if (valid) {
    x = v[3 * (size_t)e + 0];
    y = v[3 * (size_t)e + 1];
    z = v[3 * (size_t)e + 2];
  }
  float rr = sqrtf(x * x + y * y + z * z);
  float ir = 1.0f / (rr + EPSF);
  float rb[8];
  radial(rr, ir, rb);

  float ux = x * ir, uy = y * ir, uz = z * ir;
  float xx = ux * ux, yy = uy * uy, zz = uz * uz;

  float sh[M];
  if constexpr (L == 1) {
    const float c1 = 0.48860251190291992f;
    sh[0] = c1 * uy;
    sh[1] = c1 * uz;
    sh[2] = c1 * ux;
  } else if constexpr (L == 2) {
    const float c2a = 1.09254843059207907f;
    const float c2b = 0.31539156525252001f;
    const float c2c = 0.54627421529603953f;
    sh[0] = c2a * ux * uy;
    sh[1] = c2a * uy * uz;
    sh[2] = c2b * (2.0f * zz - xx - yy);
    sh[3] = c2a * ux * uz;
    sh[4] = c2c * (xx - yy);
  } else {
    const float c3a = 0.59004358992664352f;
    const float c3b = 2.89061144264055405f;
    const float c3c = 0.45704579946446574f;
    const float c3d = 0.37317633259011546f;
    const float c3e = 1.44530572132027702f;
    sh[0] = c3a * uy * (3.0f * xx - yy);
    sh[1] = c3b * ux * uy * uz;
    sh[2] = c3c * uy * (4.0f * zz - xx - yy);
    sh[3] = c3d * uz * (2.0f * zz - 3.0f * xx - 3.0f * yy);
    sh[4] = c3c * ux * (4.0f * zz - xx - yy);
    sh[5] = c3e * uz * (xx - yy);
    sh[6] = c3a * ux * (xx - 3.0f * yy);
  }

  float vals[S];
#pragma unroll
  for (int m = 0; m < M; ++m)
#pragma unroll
    for (int n = 0; n < NM; ++n) vals[m * NM + n] = sh[m] * rb[n];

  if (fullwave) {
    float* lw = reinterpret_cast<float*>(l4);
#pragma unroll
    for (int i = 0; i < S; ++i) lw[lane * S + i] = vals[i];
    fx4* g4 = reinterpret_cast<fx4*>(secbase + (size_t)e0 * S);
    constexpr int NF4 = 16 * S;
    constexpr int NITER = (NF4 + 63) / 64;
#pragma unroll
    for (int it = 0; it < NITER; ++it) {
      int k = lane + it * 64;
      if ((NF4 % 64 == 0) || k < NF4) g4[k] = l4[k];
    }
  } else if (valid) {
    float* o = secbase + (size_t)e * S;
#pragma unroll
    for (int i = 0; i < S; ++i) o[i] = vals[i];
  }
}

__global__ __launch_bounds__(256) void vexp_fused(const float* __restrict__ v,
                                                  float* __restrict__ out,
                                                  int E, int gsec) {
  __shared__ fx4 lbuf[4][560];  // 35.8 KB -> 4 blocks/CU
  const int bid = blockIdx.x;
  const int lane = threadIdx.x & 63;
  const int wave = threadIdx.x >> 6;
  const size_t E_ = (size_t)E;

  if (bid < gsec) {
    // ---- section 0: [E,1,8]. Thread-per-fx4, 2 grid-stride iters, no LDS.
    const long long n4 = 2LL * E;
    const float y0c = 0.28209479177387814f;
#pragma unroll
    for (int k = 0; k < 2; ++k) {
      long long t = (long long)bid * 256 + threadIdx.x + (long long)k * gsec * 256;
      if (t < n4) {
        long long e = t >> 1;
        int half = (int)(t & 1);
        float x = v[3 * e + 0], y = v[3 * e + 1], z = v[3 * e + 2];
        float rr = sqrtf(x * x + y * y + z * z);
        float ir = 1.0f / (rr + EPSF);
        float rb[8];
        radial(rr, ir, rb);
        int o = 4 * half;
        fx4 val = {y0c * rb[o], y0c * rb[o + 1], y0c * rb[o + 2],
                   y0c * rb[o + 3]};
        reinterpret_cast<fx4*>(out)[t] = val;
      }
    }
  } else if (bid < 2 * gsec) {
    do_section<1>(v, out + 8 * E_, E, bid - gsec, lbuf[wave], lane, wave);
  } else if (bid < 3 * gsec) {
    do_section<2>(v, out + 29 * E_, E, bid - 2 * gsec, lbuf[wave], lane, wave);
  } else {
    do_section<3>(v, out + 59 * E_, E, bid - 3 * gsec, lbuf[wave], lane, wave);
  }
}

extern "C" void kernel_launch(void* const* d_in, const int* in_sizes, int n_in,
                              void* d_out, int out_size, void* d_ws, size_t ws_size,
                              hipStream_t stream) {
  const float* v = (const float*)d_in[0];
  float* out = (float*)d_out;
  int E = in_sizes[0] / 3;
  int waves = (E + 63) / 64;
  int gsec = (waves + 3) / 4;  // 256-edge tasks per section
  vexp_fused<<<4 * gsec, 256, 0, stream>>>(v, out, E, gsec);
}